// Round 13
// baseline (242.618 us; speedup 1.0000x reference)
//
#include <hip/hip_runtime.h>
#include <math.h>

#define Nn 64
#define Tt 200
#define Bb 64

__device__ __forceinline__ float sigm(float x){ return 1.0f/(1.0f+__expf(-x)); }
__device__ __forceinline__ float tanh_fast(float x){
  x = fminf(fmaxf(x, -15.f), 15.f);
  float e = __expf(-2.f*x);
  return (1.f - e)/(1.f + e);
}

typedef __attribute__((ext_vector_type(2))) _Float16 h2v;
typedef __attribute__((ext_vector_type(4))) float f4;

// fp16 dot2 with fp32 accumulate (v_dot2_f32_f16).
#if __has_builtin(__builtin_amdgcn_fdot2)
#define DOT2(w,hv,acc) __builtin_amdgcn_fdot2((w),(hv),(acc),false)
#else
#define DOT2(w,hv,acc) fmaf((float)(w)[0],(float)(hv)[0], fmaf((float)(w)[1],(float)(hv)[1],(acc)))
#endif

// ---------------------------------------------------------------------------
// K1: build graph operators. L = -S_cheb, L2 = 2*S@S - I, G = S_gcn (+diag).
// ---------------------------------------------------------------------------
__global__ __launch_bounds__(256) void k1_graphs(
    const int* __restrict__ sp_ei, const float* __restrict__ sp_ew,
    const int* __restrict__ fn_ei, const float* __restrict__ fn_ew,
    float* __restrict__ Lg, float* __restrict__ L2g, float* __restrict__ Gm)
{
  __shared__ float deg[Nn];
  __shared__ float dinv[Nn];
  __shared__ float S[64*68];            // padded stride 68
  const int tid = threadIdx.x;

  // ---- ChebConv operator (512 edges) ----
  if (tid < Nn) deg[tid] = 0.f;
  for (int i=tid;i<64*68;i+=256) S[i]=0.f;
  __syncthreads();
  for (int e=tid;e<512;e+=256) atomicAdd(&deg[sp_ei[e]], sp_ew[e]);   // deg over row
  __syncthreads();
  if (tid < Nn) dinv[tid] = (deg[tid] > 0.f) ? rsqrtf(deg[tid]) : 0.f;
  __syncthreads();
  for (int e=tid;e<512;e+=256) {
    int r = sp_ei[e], c = sp_ei[512+e];
    atomicAdd(&S[c*68 + r], dinv[r]*sp_ew[e]*dinv[c]);
  }
  __syncthreads();
  for (int i=tid;i<4096;i+=256) Lg[i] = -S[(i>>6)*68 + (i&63)];   // Ltil = -S
  {
    const int n = tid>>2, mb = (tid&3)*16;
    float a[16];
    #pragma unroll
    for (int q=0;q<16;q++) a[q]=0.f;
    for (int j=0;j<64;j++){
      float snj = S[n*68+j];
      const float4* rj = (const float4*)&S[j*68+mb];
      #pragma unroll
      for (int q=0;q<4;q++){
        float4 v = rj[q];
        a[q*4+0]=fmaf(snj,v.x,a[q*4+0]);
        a[q*4+1]=fmaf(snj,v.y,a[q*4+1]);
        a[q*4+2]=fmaf(snj,v.z,a[q*4+2]);
        a[q*4+3]=fmaf(snj,v.w,a[q*4+3]);
      }
    }
    #pragma unroll
    for (int q=0;q<16;q++){
      int m = mb+q;
      L2g[n*64+m] = 2.f*a[q] - (n==m ? 1.f : 0.f);
    }
  }
  __syncthreads();   // all reads of S done before reuse

  // ---- GCNConv operator (1024 edges) ----
  if (tid < Nn) deg[tid] = 0.f;
  for (int i=tid;i<64*68;i+=256) S[i]=0.f;
  __syncthreads();
  for (int e=tid;e<1024;e+=256) atomicAdd(&deg[fn_ei[1024+e]], fn_ew[e]);  // deg over col
  __syncthreads();
  if (tid < Nn) dinv[tid] = rsqrtf(deg[tid] + 1.f);
  __syncthreads();
  for (int e=tid;e<1024;e+=256) {
    int r = fn_ei[e], c = fn_ei[1024+e];
    atomicAdd(&S[c*68 + r], dinv[r]*fn_ew[e]*dinv[c]);
  }
  __syncthreads();
  if (tid < Nn) S[tid*68 + tid] += dinv[tid]*dinv[tid];     // + diag(1/deg)
  __syncthreads();
  for (int i=tid;i<4096;i+=256) Gm[i] = S[(i>>6)*68 + (i&63)];
}

// ---------------------------------------------------------------------------
// K2: fold Wih (+Wcheb/Wgcn/graph ops) into Aeff[384][64] and constv[384].
// ---------------------------------------------------------------------------
__global__ __launch_bounds__(64) void k2_aeff(
    const float* __restrict__ Wih_f, const float* __restrict__ bih_f,
    const float* __restrict__ Wih_b, const float* __restrict__ bih_b,
    const float* __restrict__ Wcheb, const float* __restrict__ bcheb,
    const float* __restrict__ Wgcn,  const float* __restrict__ bgcn,
    const float* __restrict__ Lg, const float* __restrict__ L2g,
    const float* __restrict__ Gm,
    float* __restrict__ Aeff, float* __restrict__ constv)
{
  const int g = blockIdx.x;                 // 0..383
  const int dir = (g >= 192) ? 1 : 0;
  const int grow = dir ? g - 192 : g;
  const float* Wih = dir ? Wih_b : Wih_f;
  const float* bih = dir ? bih_b : bih_f;

  __shared__ float wrow[64*129];
  __shared__ float arow[256];
  const int tid = threadIdx.x;              // 64 threads = 1 wave

  for (int i = tid; i < 8192; i += 64)
    wrow[(i>>7)*129 + (i&127)] = Wih[grow*8192 + i];
  __syncthreads();

  const int n = tid;
  float a0=0.f,a1=0.f,a2=0.f,a3=0.f,cp=0.f;
  for (int c=0;c<64;c++) {
    float w1 = wrow[n*129 + c];
    a0 = fmaf(w1, Wcheb[c],     a0);
    a1 = fmaf(w1, Wcheb[64+c],  a1);
    a2 = fmaf(w1, Wcheb[128+c], a2);
    cp = fmaf(w1, bcheb[c],     cp);
    float w2 = wrow[n*129 + 64 + c];
    a3 = fmaf(w2, Wgcn[c], a3);
    cp = fmaf(w2, bgcn[c], cp);
  }
  arow[n*4+0]=a0; arow[n*4+1]=a1; arow[n*4+2]=a2; arow[n*4+3]=a3;
  for (int off=32; off; off>>=1) cp += __shfl_down(cp, off, 64);
  if (tid==0) constv[g] = cp + bih[grow];
  __syncthreads();

  const int m = tid;
  float ae = arow[m*4+0];
  for (int nn2=0; nn2<64; nn2++) {
    ae = fmaf(arow[nn2*4+1], Lg [nn2*64+m], ae);
    ae = fmaf(arow[nn2*4+2], L2g[nn2*64+m], ae);
    ae = fmaf(arow[nn2*4+3], Gm [nn2*64+m], ae);
  }
  Aeff[g*64+m] = ae;
}

// ---------------------------------------------------------------------------
// K4: xp[12800][384] = X[12800][64] @ Aeff[384][64]^T + constv, with the
// x transpose fused into staging (k3 eliminated).
// ---------------------------------------------------------------------------
__global__ __launch_bounds__(256) void k4_gemm(
    const float* __restrict__ x, const float* __restrict__ Aeff,
    const float* __restrict__ constv, float* __restrict__ xp)
{
  const int m0 = blockIdx.x*64, g0 = blockIdx.y*64;
  __shared__ float sX[64*68];   // [k][m-row], stride 68
  __shared__ float sA[64*68];   // [k][g-row]
  const int tid = threadIdx.x;

  // ---- stage X tile with fused transpose ----
  {
    const int row = tid & 63;            // lane = row (t-direction)
    const int kq  = tid >> 6;            // 0..3
    const int m = m0 + row;
    const int b = m / 200;
    const int t = m - b*200;
    const float* xb = x + (size_t)b*64*200 + t;
    #pragma unroll
    for (int kk=0; kk<16; ++kk) {
      int k = kq*16 + kk;
      sX[k*68 + row] = xb[(size_t)k*200];
    }
  }
  // ---- stage Aeff tile (float4 loads) ----
  {
    const float4* A4 = (const float4*)Aeff;
    #pragma unroll
    for (int i=0;i<4;i++) {
      int f = tid + i*256;
      int r2 = f >> 4, kq2 = f & 15;
      float4 w = A4[(g0+r2)*16 + kq2];
      sA[(kq2*4+0)*68 + r2] = w.x;
      sA[(kq2*4+1)*68 + r2] = w.y;
      sA[(kq2*4+2)*68 + r2] = w.z;
      sA[(kq2*4+3)*68 + r2] = w.w;
    }
  }
  __syncthreads();

  const int tm = tid & 15, tn = tid >> 4;
  float acc[4][4] = {};
  #pragma unroll 8
  for (int k=0;k<64;k++) {
    float4 a  = *(const float4*)&sX[k*68 + tm*4];
    float4 bb = *(const float4*)&sA[k*68 + tn*4];
    float av[4]={a.x,a.y,a.z,a.w}, bv[4]={bb.x,bb.y,bb.z,bb.w};
    #pragma unroll
    for (int i=0;i<4;i++)
      #pragma unroll
      for (int j=0;j<4;j++)
        acc[i][j] = fmaf(av[i], bv[j], acc[i][j]);
  }

  float cv[4];
  #pragma unroll
  for (int j=0;j<4;j++) cv[j] = constv[g0 + tn*4 + j];
  #pragma unroll
  for (int i=0;i<4;i++) {
    int mrow = m0 + tm*4 + i;
    #pragma unroll
    for (int j=0;j<4;j++)
      xp[mrow*384 + g0 + tn*4 + j] = acc[i][j] + cv[j];
  }
}

// ---------------------------------------------------------------------------
// K5: biGRU recurrence, DUAL-STREAM single wave. 64 blocks = batch b; one
// wave runs BOTH directions (independent chains) interleaved, so each
// stream's stall cycles (LDS round-trip, dot2 latency, transcendental chain
// — the 40% stall measured in R12: VALUBusy 7.5% of 12.5% cap) are filled
// by the other stream's issue. Lane g owns hidden unit g of both streams;
// weights resident: 2 x 96 fp16-pair regs (waves_per_eu(1,1) -> no remat,
// no spill through ~450 regs per m08).
// ---------------------------------------------------------------------------
__global__ __launch_bounds__(64)
__attribute__((amdgpu_waves_per_eu(1, 1)))
void k5_gru(
    const float* __restrict__ xp,
    const float* __restrict__ Whh_f, const float* __restrict__ bhh_f,
    const float* __restrict__ Whh_b, const float* __restrict__ bhh_b,
    float* __restrict__ gru_out)
{
  const int b = blockIdx.x;             // 0..63
  const int g = threadIdx.x & 63;

  // resident fp16-packed weight rows, both directions
  h2v wrF[32], wzF[32], wnF[32], wrB[32], wzB[32], wnB[32];
  #pragma unroll
  for (int i=0;i<32;i++){
    float2 a = ((const float2*)(Whh_f + (size_t)g*64))[i];
    float2 c = ((const float2*)(Whh_f + (size_t)(64+g)*64))[i];
    float2 d = ((const float2*)(Whh_f + (size_t)(128+g)*64))[i];
    wrF[i] = h2v{(_Float16)a.x, (_Float16)a.y};
    wzF[i] = h2v{(_Float16)c.x, (_Float16)c.y};
    wnF[i] = h2v{(_Float16)d.x, (_Float16)d.y};
    float2 a2 = ((const float2*)(Whh_b + (size_t)g*64))[i];
    float2 c2 = ((const float2*)(Whh_b + (size_t)(64+g)*64))[i];
    float2 d2 = ((const float2*)(Whh_b + (size_t)(128+g)*64))[i];
    wrB[i] = h2v{(_Float16)a2.x, (_Float16)a2.y};
    wzB[i] = h2v{(_Float16)c2.x, (_Float16)c2.y};
    wnB[i] = h2v{(_Float16)d2.x, (_Float16)d2.y};
  }
  const float brF = bhh_f[g], bzF = bhh_f[64+g], bnF = bhh_f[128+g];
  const float brB = bhh_b[g], bzB = bhh_b[64+g], bnB = bhh_b[128+g];

  __shared__ __align__(16) _Float16 hshF[64];
  __shared__ __align__(16) _Float16 hshB[64];
  hshF[g] = (_Float16)0.f;
  hshB[g] = (_Float16)0.f;

  const float* xbF = xp + (size_t)(b*Tt)*384 + g;          // dir 0
  const float* xbB = xp + (size_t)(b*Tt)*384 + 192 + g;    // dir 1
  float* goF = gru_out + (size_t)(b*Tt)*128 + g;
  float* goB = gru_out + (size_t)(b*Tt)*128 + 64 + g;

  float hF = 0.f, hB = 0.f;
  // depth-2 prefetch, both streams (A: step s, B: step s+1)
  float xrFA = xbF[0],            xzFA = xbF[64],            xnFA = xbF[128];
  float xrFB = xbF[384],          xzFB = xbF[384+64],        xnFB = xbF[384+128];
  float xrBA = xbB[(size_t)199*384], xzBA = xbB[(size_t)199*384+64], xnBA = xbB[(size_t)199*384+128];
  float xrBB = xbB[(size_t)198*384], xzBB = xbB[(size_t)198*384+64], xnBB = xbB[(size_t)198*384+128];

  int tF = 0, tB = Tt-1;
  auto STEP = [&](float& xrF, float& xzF, float& xnF,
                  float& xrB, float& xzB, float& xnB){
    const float cxrF=xrF, cxzF=xzF, cxnF=xnF;
    const float cxrB=xrB, cxzB=xzB, cxnB=xnB;
    const int tpF = tF + 2, tpB = tB - 2;
    if (tpF < Tt) {                       // reload for step s+2 (stream F)
      xrF = xbF[(size_t)tpF*384]; xzF = xbF[(size_t)tpF*384+64]; xnF = xbF[(size_t)tpF*384+128];
    }
    if (tpB >= 0) {                       // reload for step s+2 (stream B)
      xrB = xbB[(size_t)tpB*384]; xzB = xbB[(size_t)tpB*384+64]; xnB = xbB[(size_t)tpB*384+128];
    }

    const uint4* hF4 = (const uint4*)hshF;
    const uint4* hB4 = (const uint4*)hshB;
    union U { uint4 v; h2v p[4]; };
    float arF0=0.f,arF1=0.f,azF0=0.f,azF1=0.f,anF0=0.f,anF1=0.f;
    float arB0=0.f,arB1=0.f,azB0=0.f,azB1=0.f,anB0=0.f,anB1=0.f;

    #pragma unroll
    for (int c=0;c<4;c++){
      U F0,F1,B0,B1;
      F0.v = hF4[2*c]; F1.v = hF4[2*c+1];
      B0.v = hB4[2*c]; B1.v = hB4[2*c+1];
      const int base = 8*c;
      #pragma unroll
      for (int j=0;j<4;j++){
        arF0=DOT2(wrF[base+j],  F0.p[j],arF0); azF0=DOT2(wzF[base+j],  F0.p[j],azF0); anF0=DOT2(wnF[base+j],  F0.p[j],anF0);
        arB0=DOT2(wrB[base+j],  B0.p[j],arB0); azB0=DOT2(wzB[base+j],  B0.p[j],azB0); anB0=DOT2(wnB[base+j],  B0.p[j],anB0);
        arF1=DOT2(wrF[base+4+j],F1.p[j],arF1); azF1=DOT2(wzF[base+4+j],F1.p[j],azF1); anF1=DOT2(wnF[base+4+j],F1.p[j],anF1);
        arB1=DOT2(wrB[base+4+j],B1.p[j],arB1); azB1=DOT2(wzB[base+4+j],B1.p[j],azB1); anB1=DOT2(wnB[base+4+j],B1.p[j],anB1);
      }
    }

    // two independent gate chains — compiler interleaves
    float rF  = sigm(cxrF + (arF0+arF1) + brF);
    float rB  = sigm(cxrB + (arB0+arB1) + brB);
    float zF  = sigm(cxzF + (azF0+azF1) + bzF);
    float zB  = sigm(cxzB + (azB0+azB1) + bzB);
    float nF  = tanh_fast(cxnF + rF*((anF0+anF1) + bnF));
    float nB  = tanh_fast(cxnB + rB*((anB0+anB1) + bnB));
    float hnF = (1.f - zF)*nF + zF*hF;
    float hnB = (1.f - zB)*nB + zB*hB;
    hF = hnF; hB = hnB;
    hshF[g] = (_Float16)hnF;              // ds_write_b16 for next step
    hshB[g] = (_Float16)hnB;
    goF[(size_t)tF*128] = hnF;
    goB[(size_t)tB*128] = hnB;
    tF++; tB--;
  };

  for (int sp=0; sp<Tt; sp+=2) {
    STEP(xrFA,xzFA,xnFA, xrBA,xzBA,xnBA);
    STEP(xrFB,xzFB,xnFB, xrBB,xzBB,xnBB);
  }
}

// ---------------------------------------------------------------------------
// K6: attention pooling + classifier. One block per batch item.
// ---------------------------------------------------------------------------
__global__ __launch_bounds__(256) void k6_attn(
    const float* __restrict__ gru_out,
    const float* __restrict__ attn_W, const float* __restrict__ attn_b,
    const float* __restrict__ clf_W,  const float* __restrict__ clf_b,
    float* __restrict__ out)
{
  const int b = blockIdx.x, tid = threadIdx.x;
  __shared__ float s_s[Tt];
  __shared__ float red[256];
  __shared__ float aW[128], cW[128];
  if (tid < 128) { aW[tid]=attn_W[tid]; cW[tid]=clf_W[tid]; }
  __syncthreads();

  if (tid < Tt) {
    const float* row = gru_out + (b*Tt + tid)*128;
    float acc = 0.f;
    for (int j=0;j<128;j++) acc = fmaf(row[j], aW[j], acc);
    s_s[tid] = tanhf(acc + attn_b[0]);
  }
  __syncthreads();

  red[tid] = (tid < Tt) ? s_s[tid] : -1e30f;
  __syncthreads();
  for (int s2=128;s2;s2>>=1){ if(tid<s2) red[tid]=fmaxf(red[tid],red[tid+s2]); __syncthreads(); }
  float mx = red[0];
  __syncthreads();

  float e = 0.f;
  if (tid < Tt) { e = expf(s_s[tid]-mx); s_s[tid] = e; }
  red[tid] = e;
  __syncthreads();
  for (int s2=128;s2;s2>>=1){ if(tid<s2) red[tid]+=red[tid+s2]; __syncthreads(); }
  float total = red[0];
  __syncthreads();

  float p = 0.f;
  if (tid < 128) {
    float c = 0.f;
    for (int t=0;t<Tt;t++) c = fmaf(s_s[t], gru_out[(b*Tt+t)*128 + tid], c);
    p = (c/total)*cW[tid];
  }
  red[tid] = p;
  __syncthreads();
  for (int s2=128;s2;s2>>=1){ if(tid<s2) red[tid]+=red[tid+s2]; __syncthreads(); }
  if (tid==0) out[b] = sigm(red[0] + clf_b[0]);
}

// ---------------------------------------------------------------------------
extern "C" void kernel_launch(void* const* d_in, const int* in_sizes, int n_in,
                              void* d_out, int out_size, void* d_ws, size_t ws_size,
                              hipStream_t stream)
{
  const float* x      = (const float*)d_in[0];
  const int*   sp_ei  = (const int*)  d_in[1];
  const float* sp_ew  = (const float*)d_in[2];
  const int*   fn_ei  = (const int*)  d_in[3];
  const float* fn_ew  = (const float*)d_in[4];
  const float* Wcheb  = (const float*)d_in[5];
  const float* bcheb  = (const float*)d_in[6];
  const float* Wgcn   = (const float*)d_in[7];
  const float* bgcn   = (const float*)d_in[8];
  const float* Wih_f  = (const float*)d_in[9];
  const float* Whh_f  = (const float*)d_in[10];
  const float* bih_f  = (const float*)d_in[11];
  const float* bhh_f  = (const float*)d_in[12];
  const float* Wih_b  = (const float*)d_in[13];
  const float* Whh_b  = (const float*)d_in[14];
  const float* bih_b  = (const float*)d_in[15];
  const float* bhh_b  = (const float*)d_in[16];
  const float* attn_W = (const float*)d_in[17];
  const float* attn_b = (const float*)d_in[18];
  const float* clf_W  = (const float*)d_in[19];
  const float* clf_b  = (const float*)d_in[20];
  float* out = (float*)d_out;

  float* ws     = (float*)d_ws;
  float* Lg     = ws;                    // 4096
  float* L2g    = Lg   + 4096;           // 4096
  float* Gm     = L2g  + 4096;           // 4096
  float* Aeff   = Gm   + 4096;           // 384*64 = 24576
  float* constv = Aeff + 24576;          // 384 (+pad to 512)
  float* xp     = constv + 512;          // 12800*384 = 4915200
  float* gro    = xp   + 4915200;        // 12800*128 = 1638400

  hipLaunchKernelGGL(k1_graphs,    dim3(1),      dim3(256), 0, stream,
                     sp_ei, sp_ew, fn_ei, fn_ew, Lg, L2g, Gm);
  hipLaunchKernelGGL(k2_aeff,      dim3(384),    dim3(64),  0, stream,
                     Wih_f, bih_f, Wih_b, bih_b, Wcheb, bcheb, Wgcn, bgcn,
                     Lg, L2g, Gm, Aeff, constv);
  hipLaunchKernelGGL(k4_gemm,      dim3(200, 6), dim3(256), 0, stream,
                     x, Aeff, constv, xp);
  hipLaunchKernelGGL(k5_gru,       dim3(64),     dim3(64),  0, stream,
                     xp, Whh_f, bhh_f, Whh_b, bhh_b, gro);
  hipLaunchKernelGGL(k6_attn,      dim3(64),     dim3(256), 0, stream,
                     gro, attn_W, attn_b, clf_W, clf_b, out);
}

// Round 14
// 208.877 us; speedup vs baseline: 1.1615x; 1.1615x over previous
//
#include <hip/hip_runtime.h>
#include <math.h>

#define Nn 64
#define Tt 200
#define Bb 64

__device__ __forceinline__ float sigm(float x){ return 1.0f/(1.0f+__expf(-x)); }
__device__ __forceinline__ float tanh_fast(float x){
  x = fminf(fmaxf(x, -15.f), 15.f);
  float e = __expf(-2.f*x);
  return (1.f - e)/(1.f + e);
}

typedef __attribute__((ext_vector_type(2))) _Float16 h2v;
typedef __attribute__((ext_vector_type(4))) float f4;

// fp16 dot2 with fp32 accumulate (v_dot2_f32_f16).
#if __has_builtin(__builtin_amdgcn_fdot2)
#define DOT2(w,hv,acc) __builtin_amdgcn_fdot2((w),(hv),(acc),false)
#else
#define DOT2(w,hv,acc) fmaf((float)(w)[0],(float)(hv)[0], fmaf((float)(w)[1],(float)(hv)[1],(acc)))
#endif

// ---------------------------------------------------------------------------
// K1: build graph operators. L = -S_cheb, L2 = 2*S@S - I, G = S_gcn (+diag).
// ---------------------------------------------------------------------------
__global__ __launch_bounds__(256) void k1_graphs(
    const int* __restrict__ sp_ei, const float* __restrict__ sp_ew,
    const int* __restrict__ fn_ei, const float* __restrict__ fn_ew,
    float* __restrict__ Lg, float* __restrict__ L2g, float* __restrict__ Gm)
{
  __shared__ float deg[Nn];
  __shared__ float dinv[Nn];
  __shared__ float S[64*68];            // padded stride 68
  const int tid = threadIdx.x;

  // ---- ChebConv operator (512 edges) ----
  if (tid < Nn) deg[tid] = 0.f;
  for (int i=tid;i<64*68;i+=256) S[i]=0.f;
  __syncthreads();
  for (int e=tid;e<512;e+=256) atomicAdd(&deg[sp_ei[e]], sp_ew[e]);   // deg over row
  __syncthreads();
  if (tid < Nn) dinv[tid] = (deg[tid] > 0.f) ? rsqrtf(deg[tid]) : 0.f;
  __syncthreads();
  for (int e=tid;e<512;e+=256) {
    int r = sp_ei[e], c = sp_ei[512+e];
    atomicAdd(&S[c*68 + r], dinv[r]*sp_ew[e]*dinv[c]);
  }
  __syncthreads();
  for (int i=tid;i<4096;i+=256) Lg[i] = -S[(i>>6)*68 + (i&63)];   // Ltil = -S
  {
    const int n = tid>>2, mb = (tid&3)*16;
    float a[16];
    #pragma unroll
    for (int q=0;q<16;q++) a[q]=0.f;
    for (int j=0;j<64;j++){
      float snj = S[n*68+j];
      const float4* rj = (const float4*)&S[j*68+mb];
      #pragma unroll
      for (int q=0;q<4;q++){
        float4 v = rj[q];
        a[q*4+0]=fmaf(snj,v.x,a[q*4+0]);
        a[q*4+1]=fmaf(snj,v.y,a[q*4+1]);
        a[q*4+2]=fmaf(snj,v.z,a[q*4+2]);
        a[q*4+3]=fmaf(snj,v.w,a[q*4+3]);
      }
    }
    #pragma unroll
    for (int q=0;q<16;q++){
      int m = mb+q;
      L2g[n*64+m] = 2.f*a[q] - (n==m ? 1.f : 0.f);
    }
  }
  __syncthreads();   // all reads of S done before reuse

  // ---- GCNConv operator (1024 edges) ----
  if (tid < Nn) deg[tid] = 0.f;
  for (int i=tid;i<64*68;i+=256) S[i]=0.f;
  __syncthreads();
  for (int e=tid;e<1024;e+=256) atomicAdd(&deg[fn_ei[1024+e]], fn_ew[e]);  // deg over col
  __syncthreads();
  if (tid < Nn) dinv[tid] = rsqrtf(deg[tid] + 1.f);
  __syncthreads();
  for (int e=tid;e<1024;e+=256) {
    int r = fn_ei[e], c = fn_ei[1024+e];
    atomicAdd(&S[c*68 + r], dinv[r]*fn_ew[e]*dinv[c]);
  }
  __syncthreads();
  if (tid < Nn) S[tid*68 + tid] += dinv[tid]*dinv[tid];     // + diag(1/deg)
  __syncthreads();
  for (int i=tid;i<4096;i+=256) Gm[i] = S[(i>>6)*68 + (i&63)];
}

// ---------------------------------------------------------------------------
// K2: fold Wih (+Wcheb/Wgcn/graph ops) into Aeff[384][64] and constv[384].
// ---------------------------------------------------------------------------
__global__ __launch_bounds__(64) void k2_aeff(
    const float* __restrict__ Wih_f, const float* __restrict__ bih_f,
    const float* __restrict__ Wih_b, const float* __restrict__ bih_b,
    const float* __restrict__ Wcheb, const float* __restrict__ bcheb,
    const float* __restrict__ Wgcn,  const float* __restrict__ bgcn,
    const float* __restrict__ Lg, const float* __restrict__ L2g,
    const float* __restrict__ Gm,
    float* __restrict__ Aeff, float* __restrict__ constv)
{
  const int g = blockIdx.x;                 // 0..383
  const int dir = (g >= 192) ? 1 : 0;
  const int grow = dir ? g - 192 : g;
  const float* Wih = dir ? Wih_b : Wih_f;
  const float* bih = dir ? bih_b : bih_f;

  __shared__ float wrow[64*129];
  __shared__ float arow[256];
  const int tid = threadIdx.x;              // 64 threads = 1 wave

  for (int i = tid; i < 8192; i += 64)
    wrow[(i>>7)*129 + (i&127)] = Wih[grow*8192 + i];
  __syncthreads();

  const int n = tid;
  float a0=0.f,a1=0.f,a2=0.f,a3=0.f,cp=0.f;
  for (int c=0;c<64;c++) {
    float w1 = wrow[n*129 + c];
    a0 = fmaf(w1, Wcheb[c],     a0);
    a1 = fmaf(w1, Wcheb[64+c],  a1);
    a2 = fmaf(w1, Wcheb[128+c], a2);
    cp = fmaf(w1, bcheb[c],     cp);
    float w2 = wrow[n*129 + 64 + c];
    a3 = fmaf(w2, Wgcn[c], a3);
    cp = fmaf(w2, bgcn[c], cp);
  }
  arow[n*4+0]=a0; arow[n*4+1]=a1; arow[n*4+2]=a2; arow[n*4+3]=a3;
  for (int off=32; off; off>>=1) cp += __shfl_down(cp, off, 64);
  if (tid==0) constv[g] = cp + bih[grow];
  __syncthreads();

  const int m = tid;
  float ae = arow[m*4+0];
  for (int nn2=0; nn2<64; nn2++) {
    ae = fmaf(arow[nn2*4+1], Lg [nn2*64+m], ae);
    ae = fmaf(arow[nn2*4+2], L2g[nn2*64+m], ae);
    ae = fmaf(arow[nn2*4+3], Gm [nn2*64+m], ae);
  }
  Aeff[g*64+m] = ae;
}

// ---------------------------------------------------------------------------
// K4: xp[12800][384] = X[12800][64] @ Aeff[384][64]^T + constv, with the
// x transpose fused into staging (k3 eliminated).
// ---------------------------------------------------------------------------
__global__ __launch_bounds__(256) void k4_gemm(
    const float* __restrict__ x, const float* __restrict__ Aeff,
    const float* __restrict__ constv, float* __restrict__ xp)
{
  const int m0 = blockIdx.x*64, g0 = blockIdx.y*64;
  __shared__ float sX[64*68];   // [k][m-row], stride 68
  __shared__ float sA[64*68];   // [k][g-row]
  const int tid = threadIdx.x;

  // ---- stage X tile with fused transpose ----
  {
    const int row = tid & 63;            // lane = row (t-direction)
    const int kq  = tid >> 6;            // 0..3
    const int m = m0 + row;
    const int b = m / 200;
    const int t = m - b*200;
    const float* xb = x + (size_t)b*64*200 + t;
    #pragma unroll
    for (int kk=0; kk<16; ++kk) {
      int k = kq*16 + kk;
      sX[k*68 + row] = xb[(size_t)k*200];
    }
  }
  // ---- stage Aeff tile (float4 loads) ----
  {
    const float4* A4 = (const float4*)Aeff;
    #pragma unroll
    for (int i=0;i<4;i++) {
      int f = tid + i*256;
      int r2 = f >> 4, kq2 = f & 15;
      float4 w = A4[(g0+r2)*16 + kq2];
      sA[(kq2*4+0)*68 + r2] = w.x;
      sA[(kq2*4+1)*68 + r2] = w.y;
      sA[(kq2*4+2)*68 + r2] = w.z;
      sA[(kq2*4+3)*68 + r2] = w.w;
    }
  }
  __syncthreads();

  const int tm = tid & 15, tn = tid >> 4;
  float acc[4][4] = {};
  #pragma unroll 8
  for (int k=0;k<64;k++) {
    float4 a  = *(const float4*)&sX[k*68 + tm*4];
    float4 bb = *(const float4*)&sA[k*68 + tn*4];
    float av[4]={a.x,a.y,a.z,a.w}, bv[4]={bb.x,bb.y,bb.z,bb.w};
    #pragma unroll
    for (int i=0;i<4;i++)
      #pragma unroll
      for (int j=0;j<4;j++)
        acc[i][j] = fmaf(av[i], bv[j], acc[i][j]);
  }

  float cv[4];
  #pragma unroll
  for (int j=0;j<4;j++) cv[j] = constv[g0 + tn*4 + j];
  #pragma unroll
  for (int i=0;i<4;i++) {
    int mrow = m0 + tm*4 + i;
    #pragma unroll
    for (int j=0;j<4;j++)
      xp[mrow*384 + g0 + tn*4 + j] = acc[i][j] + cv[j];
  }
}

// ---------------------------------------------------------------------------
// K5: biGRU recurrence, DUAL-BATCH single wave with SHARED weights.
// 64 blocks = (batch-pair p, dir); one wave runs TWO BATCHES of the SAME
// direction. Whh is identical for both -> weights counted ONCE (96 regs),
// unlike R13's dual-direction (2x96 -> 230-reg request -> allocator cap
// ~150 -> in-loop spill, 194us). Budget here ~160: 96 w + 12 acc + 12 x +
// 16 hv (chunked) + misc. The second stream fills the first's stall cycles
// (R12 measured: single stream issues only 60% of cycles).
// ---------------------------------------------------------------------------
__global__ __launch_bounds__(64)
__attribute__((amdgpu_waves_per_eu(1, 1)))
void k5_gru(
    const float* __restrict__ xp,
    const float* __restrict__ Whh_f, const float* __restrict__ bhh_f,
    const float* __restrict__ Whh_b, const float* __restrict__ bhh_b,
    float* __restrict__ gru_out)
{
  const int bid = blockIdx.x;           // 0..63
  const int dir = bid & 1;
  const int b0 = (bid >> 1)*2, b1 = b0 + 1;
  const int g = threadIdx.x & 63;
  const float* Whh = dir ? Whh_b : Whh_f;
  const float* bhh = dir ? bhh_b : bhh_f;

  // resident fp16-packed weight rows — SHARED by both streams
  h2v wr[32], wz[32], wn[32];
  #pragma unroll
  for (int i=0;i<32;i++){
    float2 a = ((const float2*)(Whh + (size_t)g*64))[i];
    float2 bq= ((const float2*)(Whh + (size_t)(64+g)*64))[i];
    float2 c = ((const float2*)(Whh + (size_t)(128+g)*64))[i];
    wr[i] = h2v{(_Float16)a.x, (_Float16)a.y};
    wz[i] = h2v{(_Float16)bq.x,(_Float16)bq.y};
    wn[i] = h2v{(_Float16)c.x, (_Float16)c.y};
  }
  const float br_ = bhh[g], bz_ = bhh[64+g], bn_ = bhh[128+g];

  __shared__ __align__(16) _Float16 h0sh[64];
  __shared__ __align__(16) _Float16 h1sh[64];
  h0sh[g] = (_Float16)0.f;
  h1sh[g] = (_Float16)0.f;

  const int t0 = dir ? (Tt-1) : 0;
  const int tstep = dir ? -1 : 1;
  const float* xb0 = xp + (size_t)(b0*Tt)*384 + dir*192 + g;
  const float* xb1 = xp + (size_t)(b1*Tt)*384 + dir*192 + g;
  float* go0 = gru_out + (size_t)(b0*Tt)*128 + dir*64 + g;
  float* go1 = gru_out + (size_t)(b1*Tt)*128 + dir*64 + g;

  float h0 = 0.f, h1 = 0.f;
  const int t1i = t0 + tstep;
  // depth-2 prefetch, both streams, named A/B (no rotation)
  float x0rA = xb0[(size_t)t0*384],  x0zA = xb0[(size_t)t0*384+64],  x0nA = xb0[(size_t)t0*384+128];
  float x0rB = xb0[(size_t)t1i*384], x0zB = xb0[(size_t)t1i*384+64], x0nB = xb0[(size_t)t1i*384+128];
  float x1rA = xb1[(size_t)t0*384],  x1zA = xb1[(size_t)t0*384+64],  x1nA = xb1[(size_t)t0*384+128];
  float x1rB = xb1[(size_t)t1i*384], x1zB = xb1[(size_t)t1i*384+64], x1nB = xb1[(size_t)t1i*384+128];

  int t = t0;
  auto STEP = [&](float& x0r, float& x0z, float& x0n,
                  float& x1r, float& x1z, float& x1n){
    const float c0r=x0r, c0z=x0z, c0n=x0n;
    const float c1r=x1r, c1z=x1z, c1n=x1n;
    const int tpre = t + 2*tstep;
    if ((unsigned)tpre < (unsigned)Tt) {   // reload for step s+2, both streams
      x0r = xb0[(size_t)tpre*384]; x0z = xb0[(size_t)tpre*384+64]; x0n = xb0[(size_t)tpre*384+128];
      x1r = xb1[(size_t)tpre*384]; x1z = xb1[(size_t)tpre*384+64]; x1n = xb1[(size_t)tpre*384+128];
    }

    const uint4* h04 = (const uint4*)h0sh;
    const uint4* h14 = (const uint4*)h1sh;
    union U { uint4 v; h2v p[4]; };
    float a0r0=0.f,a0r1=0.f,a0z0=0.f,a0z1=0.f,a0n0=0.f,a0n1=0.f;
    float a1r0=0.f,a1r1=0.f,a1z0=0.f,a1z1=0.f,a1n0=0.f,a1n1=0.f;

    // chunked: 4 chunks x (2+2 ds_read_b128), 16 hv regs live at peak;
    // 48 dot2/chunk, two independent streams interleaved by construction
    #pragma unroll
    for (int c=0;c<4;c++){
      U F0,F1,G0,G1;
      F0.v = h04[2*c]; F1.v = h04[2*c+1];
      G0.v = h14[2*c]; G1.v = h14[2*c+1];
      const int base = 8*c;
      #pragma unroll
      for (int j=0;j<4;j++){
        a0r0=DOT2(wr[base+j],  F0.p[j],a0r0); a0z0=DOT2(wz[base+j],  F0.p[j],a0z0); a0n0=DOT2(wn[base+j],  F0.p[j],a0n0);
        a1r0=DOT2(wr[base+j],  G0.p[j],a1r0); a1z0=DOT2(wz[base+j],  G0.p[j],a1z0); a1n0=DOT2(wn[base+j],  G0.p[j],a1n0);
        a0r1=DOT2(wr[base+4+j],F1.p[j],a0r1); a0z1=DOT2(wz[base+4+j],F1.p[j],a0z1); a0n1=DOT2(wn[base+4+j],F1.p[j],a0n1);
        a1r1=DOT2(wr[base+4+j],G1.p[j],a1r1); a1z1=DOT2(wz[base+4+j],G1.p[j],a1z1); a1n1=DOT2(wn[base+4+j],G1.p[j],a1n1);
      }
    }

    // two independent gate chains — compiler interleaves
    float r0  = sigm(c0r + (a0r0+a0r1) + br_);
    float r1  = sigm(c1r + (a1r0+a1r1) + br_);
    float z0  = sigm(c0z + (a0z0+a0z1) + bz_);
    float z1  = sigm(c1z + (a1z0+a1z1) + bz_);
    float n0  = tanh_fast(c0n + r0*((a0n0+a0n1) + bn_));
    float n1  = tanh_fast(c1n + r1*((a1n0+a1n1) + bn_));
    float hn0 = (1.f - z0)*n0 + z0*h0;
    float hn1 = (1.f - z1)*n1 + z1*h1;
    h0 = hn0; h1 = hn1;
    h0sh[g] = (_Float16)hn0;              // ds_write_b16 for next step
    h1sh[g] = (_Float16)hn1;
    go0[(size_t)t*128] = hn0;
    go1[(size_t)t*128] = hn1;
    t += tstep;
  };

  for (int sp=0; sp<Tt; sp+=2) {
    STEP(x0rA,x0zA,x0nA, x1rA,x1zA,x1nA);
    STEP(x0rB,x0zB,x0nB, x1rB,x1zB,x1nB);
  }
}

// ---------------------------------------------------------------------------
// K6: attention pooling + classifier. One block per batch item.
// ---------------------------------------------------------------------------
__global__ __launch_bounds__(256) void k6_attn(
    const float* __restrict__ gru_out,
    const float* __restrict__ attn_W, const float* __restrict__ attn_b,
    const float* __restrict__ clf_W,  const float* __restrict__ clf_b,
    float* __restrict__ out)
{
  const int b = blockIdx.x, tid = threadIdx.x;
  __shared__ float s_s[Tt];
  __shared__ float red[256];
  __shared__ float aW[128], cW[128];
  if (tid < 128) { aW[tid]=attn_W[tid]; cW[tid]=clf_W[tid]; }
  __syncthreads();

  if (tid < Tt) {
    const float* row = gru_out + (b*Tt + tid)*128;
    float acc = 0.f;
    for (int j=0;j<128;j++) acc = fmaf(row[j], aW[j], acc);
    s_s[tid] = tanhf(acc + attn_b[0]);
  }
  __syncthreads();

  red[tid] = (tid < Tt) ? s_s[tid] : -1e30f;
  __syncthreads();
  for (int s2=128;s2;s2>>=1){ if(tid<s2) red[tid]=fmaxf(red[tid],red[tid+s2]); __syncthreads(); }
  float mx = red[0];
  __syncthreads();

  float e = 0.f;
  if (tid < Tt) { e = expf(s_s[tid]-mx); s_s[tid] = e; }
  red[tid] = e;
  __syncthreads();
  for (int s2=128;s2;s2>>=1){ if(tid<s2) red[tid]+=red[tid+s2]; __syncthreads(); }
  float total = red[0];
  __syncthreads();

  float p = 0.f;
  if (tid < 128) {
    float c = 0.f;
    for (int t=0;t<Tt;t++) c = fmaf(s_s[t], gru_out[(b*Tt+t)*128 + tid], c);
    p = (c/total)*cW[tid];
  }
  red[tid] = p;
  __syncthreads();
  for (int s2=128;s2;s2>>=1){ if(tid<s2) red[tid]+=red[tid+s2]; __syncthreads(); }
  if (tid==0) out[b] = sigm(red[0] + clf_b[0]);
}

// ---------------------------------------------------------------------------
extern "C" void kernel_launch(void* const* d_in, const int* in_sizes, int n_in,
                              void* d_out, int out_size, void* d_ws, size_t ws_size,
                              hipStream_t stream)
{
  const float* x      = (const float*)d_in[0];
  const int*   sp_ei  = (const int*)  d_in[1];
  const float* sp_ew  = (const float*)d_in[2];
  const int*   fn_ei  = (const int*)  d_in[3];
  const float* fn_ew  = (const float*)d_in[4];
  const float* Wcheb  = (const float*)d_in[5];
  const float* bcheb  = (const float*)d_in[6];
  const float* Wgcn   = (const float*)d_in[7];
  const float* bgcn   = (const float*)d_in[8];
  const float* Wih_f  = (const float*)d_in[9];
  const float* Whh_f  = (const float*)d_in[10];
  const float* bih_f  = (const float*)d_in[11];
  const float* bhh_f  = (const float*)d_in[12];
  const float* Wih_b  = (const float*)d_in[13];
  const float* Whh_b  = (const float*)d_in[14];
  const float* bih_b  = (const float*)d_in[15];
  const float* bhh_b  = (const float*)d_in[16];
  const float* attn_W = (const float*)d_in[17];
  const float* attn_b = (const float*)d_in[18];
  const float* clf_W  = (const float*)d_in[19];
  const float* clf_b  = (const float*)d_in[20];
  float* out = (float*)d_out;

  float* ws     = (float*)d_ws;
  float* Lg     = ws;                    // 4096
  float* L2g    = Lg   + 4096;           // 4096
  float* Gm     = L2g  + 4096;           // 4096
  float* Aeff   = Gm   + 4096;           // 384*64 = 24576
  float* constv = Aeff + 24576;          // 384 (+pad to 512)
  float* xp     = constv + 512;          // 12800*384 = 4915200
  float* gro    = xp   + 4915200;        // 12800*128 = 1638400

  hipLaunchKernelGGL(k1_graphs,    dim3(1),      dim3(256), 0, stream,
                     sp_ei, sp_ew, fn_ei, fn_ew, Lg, L2g, Gm);
  hipLaunchKernelGGL(k2_aeff,      dim3(384),    dim3(64),  0, stream,
                     Wih_f, bih_f, Wih_b, bih_b, Wcheb, bcheb, Wgcn, bgcn,
                     Lg, L2g, Gm, Aeff, constv);
  hipLaunchKernelGGL(k4_gemm,      dim3(200, 6), dim3(256), 0, stream,
                     x, Aeff, constv, xp);
  hipLaunchKernelGGL(k5_gru,       dim3(64),     dim3(64),  0, stream,
                     xp, Whh_f, bhh_f, Whh_b, bhh_b, gro);
  hipLaunchKernelGGL(k6_attn,      dim3(64),     dim3(256), 0, stream,
                     gro, attn_W, attn_b, clf_W, clf_b, out);
}

// Round 15
// 202.373 us; speedup vs baseline: 1.1989x; 1.0321x over previous
//
#include <hip/hip_runtime.h>
#include <math.h>

#define Nn 64
#define Tt 200
#define Bb 64

__device__ __forceinline__ float sigm(float x){ return 1.0f/(1.0f+__expf(-x)); }
__device__ __forceinline__ float tanh_fast(float x){
  x = fminf(fmaxf(x, -15.f), 15.f);
  float e = __expf(-2.f*x);
  return (1.f - e)/(1.f + e);
}

typedef __attribute__((ext_vector_type(2))) _Float16 h2v;
typedef __attribute__((ext_vector_type(4))) float f4;

// fp16 dot2 with fp32 accumulate (v_dot2_f32_f16).
#if __has_builtin(__builtin_amdgcn_fdot2)
#define DOT2(w,hv,acc) __builtin_amdgcn_fdot2((w),(hv),(acc),false)
#else
#define DOT2(w,hv,acc) fmaf((float)(w)[0],(float)(hv)[0], fmaf((float)(w)[1],(float)(hv)[1],(acc)))
#endif

// ---------------------------------------------------------------------------
// K1: build graph operators. L = -S_cheb, L2 = 2*S@S - I, G = S_gcn (+diag).
// ---------------------------------------------------------------------------
__global__ __launch_bounds__(256) void k1_graphs(
    const int* __restrict__ sp_ei, const float* __restrict__ sp_ew,
    const int* __restrict__ fn_ei, const float* __restrict__ fn_ew,
    float* __restrict__ Lg, float* __restrict__ L2g, float* __restrict__ Gm)
{
  __shared__ float deg[Nn];
  __shared__ float dinv[Nn];
  __shared__ float S[64*68];            // padded stride 68
  const int tid = threadIdx.x;

  // ---- ChebConv operator (512 edges) ----
  if (tid < Nn) deg[tid] = 0.f;
  for (int i=tid;i<64*68;i+=256) S[i]=0.f;
  __syncthreads();
  for (int e=tid;e<512;e+=256) atomicAdd(&deg[sp_ei[e]], sp_ew[e]);   // deg over row
  __syncthreads();
  if (tid < Nn) dinv[tid] = (deg[tid] > 0.f) ? rsqrtf(deg[tid]) : 0.f;
  __syncthreads();
  for (int e=tid;e<512;e+=256) {
    int r = sp_ei[e], c = sp_ei[512+e];
    atomicAdd(&S[c*68 + r], dinv[r]*sp_ew[e]*dinv[c]);
  }
  __syncthreads();
  for (int i=tid;i<4096;i+=256) Lg[i] = -S[(i>>6)*68 + (i&63)];   // Ltil = -S
  {
    const int n = tid>>2, mb = (tid&3)*16;
    float a[16];
    #pragma unroll
    for (int q=0;q<16;q++) a[q]=0.f;
    for (int j=0;j<64;j++){
      float snj = S[n*68+j];
      const float4* rj = (const float4*)&S[j*68+mb];
      #pragma unroll
      for (int q=0;q<4;q++){
        float4 v = rj[q];
        a[q*4+0]=fmaf(snj,v.x,a[q*4+0]);
        a[q*4+1]=fmaf(snj,v.y,a[q*4+1]);
        a[q*4+2]=fmaf(snj,v.z,a[q*4+2]);
        a[q*4+3]=fmaf(snj,v.w,a[q*4+3]);
      }
    }
    #pragma unroll
    for (int q=0;q<16;q++){
      int m = mb+q;
      L2g[n*64+m] = 2.f*a[q] - (n==m ? 1.f : 0.f);
    }
  }
  __syncthreads();   // all reads of S done before reuse

  // ---- GCNConv operator (1024 edges) ----
  if (tid < Nn) deg[tid] = 0.f;
  for (int i=tid;i<64*68;i+=256) S[i]=0.f;
  __syncthreads();
  for (int e=tid;e<1024;e+=256) atomicAdd(&deg[fn_ei[1024+e]], fn_ew[e]);  // deg over col
  __syncthreads();
  if (tid < Nn) dinv[tid] = rsqrtf(deg[tid] + 1.f);
  __syncthreads();
  for (int e=tid;e<1024;e+=256) {
    int r = fn_ei[e], c = fn_ei[1024+e];
    atomicAdd(&S[c*68 + r], dinv[r]*fn_ew[e]*dinv[c]);
  }
  __syncthreads();
  if (tid < Nn) S[tid*68 + tid] += dinv[tid]*dinv[tid];     // + diag(1/deg)
  __syncthreads();
  for (int i=tid;i<4096;i+=256) Gm[i] = S[(i>>6)*68 + (i&63)];
}

// ---------------------------------------------------------------------------
// K2: fold Wih (+Wcheb/Wgcn/graph ops) into Aeff[384][64] and constv[384].
// ---------------------------------------------------------------------------
__global__ __launch_bounds__(64) void k2_aeff(
    const float* __restrict__ Wih_f, const float* __restrict__ bih_f,
    const float* __restrict__ Wih_b, const float* __restrict__ bih_b,
    const float* __restrict__ Wcheb, const float* __restrict__ bcheb,
    const float* __restrict__ Wgcn,  const float* __restrict__ bgcn,
    const float* __restrict__ Lg, const float* __restrict__ L2g,
    const float* __restrict__ Gm,
    float* __restrict__ Aeff, float* __restrict__ constv)
{
  const int g = blockIdx.x;                 // 0..383
  const int dir = (g >= 192) ? 1 : 0;
  const int grow = dir ? g - 192 : g;
  const float* Wih = dir ? Wih_b : Wih_f;
  const float* bih = dir ? bih_b : bih_f;

  __shared__ float wrow[64*129];
  __shared__ float arow[256];
  const int tid = threadIdx.x;              // 64 threads = 1 wave

  for (int i = tid; i < 8192; i += 64)
    wrow[(i>>7)*129 + (i&127)] = Wih[grow*8192 + i];
  __syncthreads();

  const int n = tid;
  float a0=0.f,a1=0.f,a2=0.f,a3=0.f,cp=0.f;
  for (int c=0;c<64;c++) {
    float w1 = wrow[n*129 + c];
    a0 = fmaf(w1, Wcheb[c],     a0);
    a1 = fmaf(w1, Wcheb[64+c],  a1);
    a2 = fmaf(w1, Wcheb[128+c], a2);
    cp = fmaf(w1, bcheb[c],     cp);
    float w2 = wrow[n*129 + 64 + c];
    a3 = fmaf(w2, Wgcn[c], a3);
    cp = fmaf(w2, bgcn[c], cp);
  }
  arow[n*4+0]=a0; arow[n*4+1]=a1; arow[n*4+2]=a2; arow[n*4+3]=a3;
  for (int off=32; off; off>>=1) cp += __shfl_down(cp, off, 64);
  if (tid==0) constv[g] = cp + bih[grow];
  __syncthreads();

  const int m = tid;
  float ae = arow[m*4+0];
  for (int nn2=0; nn2<64; nn2++) {
    ae = fmaf(arow[nn2*4+1], Lg [nn2*64+m], ae);
    ae = fmaf(arow[nn2*4+2], L2g[nn2*64+m], ae);
    ae = fmaf(arow[nn2*4+3], Gm [nn2*64+m], ae);
  }
  Aeff[g*64+m] = ae;
}

// ---------------------------------------------------------------------------
// K4: xp[12800][384] = X[12800][64] @ Aeff[384][64]^T + constv, with the
// x transpose fused into staging (k3 eliminated).
// ---------------------------------------------------------------------------
__global__ __launch_bounds__(256) void k4_gemm(
    const float* __restrict__ x, const float* __restrict__ Aeff,
    const float* __restrict__ constv, float* __restrict__ xp)
{
  const int m0 = blockIdx.x*64, g0 = blockIdx.y*64;
  __shared__ float sX[64*68];   // [k][m-row], stride 68
  __shared__ float sA[64*68];   // [k][g-row]
  const int tid = threadIdx.x;

  // ---- stage X tile with fused transpose ----
  {
    const int row = tid & 63;            // lane = row (t-direction)
    const int kq  = tid >> 6;            // 0..3
    const int m = m0 + row;
    const int b = m / 200;
    const int t = m - b*200;
    const float* xb = x + (size_t)b*64*200 + t;
    #pragma unroll
    for (int kk=0; kk<16; ++kk) {
      int k = kq*16 + kk;
      sX[k*68 + row] = xb[(size_t)k*200];
    }
  }
  // ---- stage Aeff tile (float4 loads) ----
  {
    const float4* A4 = (const float4*)Aeff;
    #pragma unroll
    for (int i=0;i<4;i++) {
      int f = tid + i*256;
      int r2 = f >> 4, kq2 = f & 15;
      float4 w = A4[(g0+r2)*16 + kq2];
      sA[(kq2*4+0)*68 + r2] = w.x;
      sA[(kq2*4+1)*68 + r2] = w.y;
      sA[(kq2*4+2)*68 + r2] = w.z;
      sA[(kq2*4+3)*68 + r2] = w.w;
    }
  }
  __syncthreads();

  const int tm = tid & 15, tn = tid >> 4;
  float acc[4][4] = {};
  #pragma unroll 8
  for (int k=0;k<64;k++) {
    float4 a  = *(const float4*)&sX[k*68 + tm*4];
    float4 bb = *(const float4*)&sA[k*68 + tn*4];
    float av[4]={a.x,a.y,a.z,a.w}, bv[4]={bb.x,bb.y,bb.z,bb.w};
    #pragma unroll
    for (int i=0;i<4;i++)
      #pragma unroll
      for (int j=0;j<4;j++)
        acc[i][j] = fmaf(av[i], bv[j], acc[i][j]);
  }

  float cv[4];
  #pragma unroll
  for (int j=0;j<4;j++) cv[j] = constv[g0 + tn*4 + j];
  #pragma unroll
  for (int i=0;i<4;i++) {
    int mrow = m0 + tm*4 + i;
    #pragma unroll
    for (int j=0;j<4;j++)
      xp[mrow*384 + g0 + tn*4 + j] = acc[i][j] + cv[j];
  }
}

// ---------------------------------------------------------------------------
// K5: biGRU recurrence — 8 INDEPENDENT single-stream wave-engines per block.
// 16 blocks x 512 threads; wave w of block p runs stream sid = p*8+w =
// (batch, dir). Each wave = R11's proven engine (96 fp16-pair weight regs,
// LDS h broadcast via ds_write_b16 + 8x broadcast ds_read_b128, no barriers).
// KEY: waves_per_eu(2,2) — two waves per SIMD co-resident, so the CU
// scheduler fills each wave's stall cycles (LDS round-trip, dot2 latency,
// transcendental chain = the 40% idle measured in R12) with the sibling
// wave's issue (m114: co-scheduled waves run at max, not sum). This is the
// dual-stream ILP idea WITHOUT doubling per-wave register demand, which the
// allocator's ~132-reg grant killed in R13/R14. Budget: 2 waves/SIMD =>
// 256 VGPR/wave (m69); need ~155 -> fits, no remat pressure.
// ---------------------------------------------------------------------------
__global__ __launch_bounds__(512)
__attribute__((amdgpu_waves_per_eu(2, 2)))
void k5_gru(
    const float* __restrict__ xp,
    const float* __restrict__ Whh_f, const float* __restrict__ bhh_f,
    const float* __restrict__ Whh_b, const float* __restrict__ bhh_b,
    float* __restrict__ gru_out)
{
  const int wid = threadIdx.x >> 6;     // wave 0..7
  const int g   = threadIdx.x & 63;
  const int sid = blockIdx.x*8 + wid;   // stream 0..127
  const int b = sid >> 1, dir = sid & 1;
  const float* Whh = dir ? Whh_b : Whh_f;
  const float* bhh = dir ? bhh_b : bhh_f;

  // resident fp16-packed weight rows (3 gate rows for this lane's unit)
  h2v wr[32], wz[32], wn[32];
  #pragma unroll
  for (int i=0;i<32;i++){
    float2 a = ((const float2*)(Whh + (size_t)g*64))[i];
    float2 bq= ((const float2*)(Whh + (size_t)(64+g)*64))[i];
    float2 c = ((const float2*)(Whh + (size_t)(128+g)*64))[i];
    wr[i] = h2v{(_Float16)a.x, (_Float16)a.y};
    wz[i] = h2v{(_Float16)bq.x,(_Float16)bq.y};
    wn[i] = h2v{(_Float16)c.x, (_Float16)c.y};
  }
  const float br_ = bhh[g], bz_ = bhh[64+g], bn_ = bhh[128+g];

  __shared__ __align__(16) _Float16 hsh[8][64];   // per-wave 128B h buffer
  hsh[wid][g] = (_Float16)0.f;                    // own buffer only; no barrier

  const int t0 = dir ? (Tt-1) : 0;
  const int tstep = dir ? -1 : 1;
  const float* xb = xp + (size_t)(b*Tt)*384 + dir*192 + g;
  float* gout = gru_out + (size_t)(b*Tt)*128 + dir*64 + g;

  float h = 0.f;
  float xrA = xb[(size_t)t0*384], xzA = xb[(size_t)t0*384+64], xnA = xb[(size_t)t0*384+128];
  const int t1 = t0 + tstep;
  float xrB = xb[(size_t)t1*384], xzB = xb[(size_t)t1*384+64], xnB = xb[(size_t)t1*384+128];

  _Float16* myh = &hsh[wid][0];
  int t = t0;
  auto STEP = [&](float& xr, float& xz, float& xn){
    // broadcast-read this wave's packed h vector: 8x ds_read_b128
    h2v hv[32];
    {
      const uint4* hp4 = (const uint4*)myh;
      #pragma unroll
      for (int q=0;q<8;q++){
        union { uint4 v; h2v p[4]; } uu;
        uu.v = hp4[q];
        hv[q*4+0]=uu.p[0]; hv[q*4+1]=uu.p[1]; hv[q*4+2]=uu.p[2]; hv[q*4+3]=uu.p[3];
      }
    }

    const float cxr = xr, cxz = xz, cxn = xn;
    const int tpre = t + 2*tstep;
    if ((unsigned)tpre < (unsigned)Tt) {   // depth-2 prefetch, reload after use
      xr = xb[(size_t)tpre*384];
      xz = xb[(size_t)tpre*384+64];
      xn = xb[(size_t)tpre*384+128];
    }

    float ar0=0.f,ar1=0.f,az0=0.f,az1=0.f,an0=0.f,an1=0.f;
    #pragma unroll
    for (int i=0;i<32;i+=2){
      ar0 = DOT2(wr[i],  hv[i],  ar0);  az0 = DOT2(wz[i],  hv[i],  az0);  an0 = DOT2(wn[i],  hv[i],  an0);
      ar1 = DOT2(wr[i+1],hv[i+1],ar1);  az1 = DOT2(wz[i+1],hv[i+1],az1);  an1 = DOT2(wn[i+1],hv[i+1],an1);
    }

    float r   = sigm(cxr + (ar0+ar1) + br_);
    float z   = sigm(cxz + (az0+az1) + bz_);
    float nn2 = tanh_fast(cxn + r*((an0+an1) + bn_));
    float hnew = (1.f - z)*nn2 + z*h;
    h = hnew;
    myh[g] = (_Float16)hnew;               // ds_write_b16 for next step
    gout[(size_t)t*128] = hnew;
    t += tstep;
  };

  for (int sp=0; sp<Tt; sp+=2) { STEP(xrA,xzA,xnA); STEP(xrB,xzB,xnB); }
}

// ---------------------------------------------------------------------------
// K6: attention pooling + classifier. One block per batch item.
// ---------------------------------------------------------------------------
__global__ __launch_bounds__(256) void k6_attn(
    const float* __restrict__ gru_out,
    const float* __restrict__ attn_W, const float* __restrict__ attn_b,
    const float* __restrict__ clf_W,  const float* __restrict__ clf_b,
    float* __restrict__ out)
{
  const int b = blockIdx.x, tid = threadIdx.x;
  __shared__ float s_s[Tt];
  __shared__ float red[256];
  __shared__ float aW[128], cW[128];
  if (tid < 128) { aW[tid]=attn_W[tid]; cW[tid]=clf_W[tid]; }
  __syncthreads();

  if (tid < Tt) {
    const float* row = gru_out + (b*Tt + tid)*128;
    float acc = 0.f;
    for (int j=0;j<128;j++) acc = fmaf(row[j], aW[j], acc);
    s_s[tid] = tanhf(acc + attn_b[0]);
  }
  __syncthreads();

  red[tid] = (tid < Tt) ? s_s[tid] : -1e30f;
  __syncthreads();
  for (int s2=128;s2;s2>>=1){ if(tid<s2) red[tid]=fmaxf(red[tid],red[tid+s2]); __syncthreads(); }
  float mx = red[0];
  __syncthreads();

  float e = 0.f;
  if (tid < Tt) { e = expf(s_s[tid]-mx); s_s[tid] = e; }
  red[tid] = e;
  __syncthreads();
  for (int s2=128;s2;s2>>=1){ if(tid<s2) red[tid]+=red[tid+s2]; __syncthreads(); }
  float total = red[0];
  __syncthreads();

  float p = 0.f;
  if (tid < 128) {
    float c = 0.f;
    for (int t=0;t<Tt;t++) c = fmaf(s_s[t], gru_out[(b*Tt+t)*128 + tid], c);
    p = (c/total)*cW[tid];
  }
  red[tid] = p;
  __syncthreads();
  for (int s2=128;s2;s2>>=1){ if(tid<s2) red[tid]+=red[tid+s2]; __syncthreads(); }
  if (tid==0) out[b] = sigm(red[0] + clf_b[0]);
}

// ---------------------------------------------------------------------------
extern "C" void kernel_launch(void* const* d_in, const int* in_sizes, int n_in,
                              void* d_out, int out_size, void* d_ws, size_t ws_size,
                              hipStream_t stream)
{
  const float* x      = (const float*)d_in[0];
  const int*   sp_ei  = (const int*)  d_in[1];
  const float* sp_ew  = (const float*)d_in[2];
  const int*   fn_ei  = (const int*)  d_in[3];
  const float* fn_ew  = (const float*)d_in[4];
  const float* Wcheb  = (const float*)d_in[5];
  const float* bcheb  = (const float*)d_in[6];
  const float* Wgcn   = (const float*)d_in[7];
  const float* bgcn   = (const float*)d_in[8];
  const float* Wih_f  = (const float*)d_in[9];
  const float* Whh_f  = (const float*)d_in[10];
  const float* bih_f  = (const float*)d_in[11];
  const float* bhh_f  = (const float*)d_in[12];
  const float* Wih_b  = (const float*)d_in[13];
  const float* Whh_b  = (const float*)d_in[14];
  const float* bih_b  = (const float*)d_in[15];
  const float* bhh_b  = (const float*)d_in[16];
  const float* attn_W = (const float*)d_in[17];
  const float* attn_b = (const float*)d_in[18];
  const float* clf_W  = (const float*)d_in[19];
  const float* clf_b  = (const float*)d_in[20];
  float* out = (float*)d_out;

  float* ws     = (float*)d_ws;
  float* Lg     = ws;                    // 4096
  float* L2g    = Lg   + 4096;           // 4096
  float* Gm     = L2g  + 4096;           // 4096
  float* Aeff   = Gm   + 4096;           // 384*64 = 24576
  float* constv = Aeff + 24576;          // 384 (+pad to 512)
  float* xp     = constv + 512;          // 12800*384 = 4915200
  float* gro    = xp   + 4915200;        // 12800*128 = 1638400

  hipLaunchKernelGGL(k1_graphs,    dim3(1),      dim3(256), 0, stream,
                     sp_ei, sp_ew, fn_ei, fn_ew, Lg, L2g, Gm);
  hipLaunchKernelGGL(k2_aeff,      dim3(384),    dim3(64),  0, stream,
                     Wih_f, bih_f, Wih_b, bih_b, Wcheb, bcheb, Wgcn, bgcn,
                     Lg, L2g, Gm, Aeff, constv);
  hipLaunchKernelGGL(k4_gemm,      dim3(200, 6), dim3(256), 0, stream,
                     x, Aeff, constv, xp);
  hipLaunchKernelGGL(k5_gru,       dim3(16),     dim3(512), 0, stream,
                     xp, Whh_f, bhh_f, Whh_b, bhh_b, gro);
  hipLaunchKernelGGL(k6_attn,      dim3(64),     dim3(256), 0, stream,
                     gro, attn_W, attn_b, clf_W, clf_b, out);
}

// Round 16
// 132.041 us; speedup vs baseline: 1.8374x; 1.5326x over previous
//
#include <hip/hip_runtime.h>
#include <math.h>

#define Nn 64
#define Tt 200
#define Bb 64

__device__ __forceinline__ float sigm(float x){ return 1.0f/(1.0f+__expf(-x)); }
__device__ __forceinline__ float tanh_fast(float x){
  x = fminf(fmaxf(x, -15.f), 15.f);
  float e = __expf(-2.f*x);
  return (1.f - e)/(1.f + e);
}

typedef __attribute__((ext_vector_type(2))) _Float16 h2v;
typedef __attribute__((ext_vector_type(4))) float f4;

// fp16 dot2 with fp32 accumulate (v_dot2_f32_f16).
#if __has_builtin(__builtin_amdgcn_fdot2)
#define DOT2(w,hv,acc) __builtin_amdgcn_fdot2((w),(hv),(acc),false)
#else
#define DOT2(w,hv,acc) fmaf((float)(w)[0],(float)(hv)[0], fmaf((float)(w)[1],(float)(hv)[1],(acc)))
#endif

// ---------------------------------------------------------------------------
// K1: build graph operators. L = -S_cheb, L2 = 2*S@S - I, G = S_gcn (+diag).
// 1024 threads (was 256): 4x parallelism in S@S and copies — the single
// block is latency-bound, more waves hide LDS latency.
// ---------------------------------------------------------------------------
__global__ __launch_bounds__(1024) void k1_graphs(
    const int* __restrict__ sp_ei, const float* __restrict__ sp_ew,
    const int* __restrict__ fn_ei, const float* __restrict__ fn_ew,
    float* __restrict__ Lg, float* __restrict__ L2g, float* __restrict__ Gm)
{
  __shared__ float deg[Nn];
  __shared__ float dinv[Nn];
  __shared__ float S[64*68];            // padded stride 68
  const int tid = threadIdx.x;

  // ---- ChebConv operator (512 edges) ----
  if (tid < Nn) deg[tid] = 0.f;
  for (int i=tid;i<64*68;i+=1024) S[i]=0.f;
  __syncthreads();
  if (tid < 512) atomicAdd(&deg[sp_ei[tid]], sp_ew[tid]);   // deg over row
  __syncthreads();
  if (tid < Nn) dinv[tid] = (deg[tid] > 0.f) ? rsqrtf(deg[tid]) : 0.f;
  __syncthreads();
  if (tid < 512) {
    int r = sp_ei[tid], c = sp_ei[512+tid];
    atomicAdd(&S[c*68 + r], dinv[r]*sp_ew[tid]*dinv[c]);
  }
  __syncthreads();
  for (int i=tid;i<4096;i+=1024) Lg[i] = -S[(i>>6)*68 + (i&63)];   // Ltil = -S
  // L2 = 2*S@S - I : thread -> row n = tid>>4, 4 cols at (tid&15)*4
  {
    const int n = tid>>4, mb = (tid&15)*4;
    float a0=0.f,a1=0.f,a2=0.f,a3=0.f;
    for (int j=0;j<64;j++){
      float snj = S[n*68+j];
      float4 v = *(const float4*)&S[j*68+mb];
      a0=fmaf(snj,v.x,a0); a1=fmaf(snj,v.y,a1);
      a2=fmaf(snj,v.z,a2); a3=fmaf(snj,v.w,a3);
    }
    L2g[n*64+mb+0] = 2.f*a0 - (n==mb+0 ? 1.f : 0.f);
    L2g[n*64+mb+1] = 2.f*a1 - (n==mb+1 ? 1.f : 0.f);
    L2g[n*64+mb+2] = 2.f*a2 - (n==mb+2 ? 1.f : 0.f);
    L2g[n*64+mb+3] = 2.f*a3 - (n==mb+3 ? 1.f : 0.f);
  }
  __syncthreads();   // all reads of S done before reuse

  // ---- GCNConv operator (1024 edges) ----
  if (tid < Nn) deg[tid] = 0.f;
  for (int i=tid;i<64*68;i+=1024) S[i]=0.f;
  __syncthreads();
  atomicAdd(&deg[fn_ei[1024+tid]], fn_ew[tid]);             // deg over col
  __syncthreads();
  if (tid < Nn) dinv[tid] = rsqrtf(deg[tid] + 1.f);
  __syncthreads();
  {
    int r = fn_ei[tid], c = fn_ei[1024+tid];
    atomicAdd(&S[c*68 + r], dinv[r]*fn_ew[tid]*dinv[c]);
  }
  __syncthreads();
  if (tid < Nn) S[tid*68 + tid] += dinv[tid]*dinv[tid];     // + diag(1/deg)
  __syncthreads();
  for (int i=tid;i<4096;i+=1024) Gm[i] = S[(i>>6)*68 + (i&63)];
}

// ---------------------------------------------------------------------------
// K2: fold Wih (+Wcheb/Wgcn/graph ops) into Aeff[384][64] and constv[384].
// float4 weight staging (32 x 16B loads/lane instead of 128 scalar).
// ---------------------------------------------------------------------------
__global__ __launch_bounds__(64) void k2_aeff(
    const float* __restrict__ Wih_f, const float* __restrict__ bih_f,
    const float* __restrict__ Wih_b, const float* __restrict__ bih_b,
    const float* __restrict__ Wcheb, const float* __restrict__ bcheb,
    const float* __restrict__ Wgcn,  const float* __restrict__ bgcn,
    const float* __restrict__ Lg, const float* __restrict__ L2g,
    const float* __restrict__ Gm,
    float* __restrict__ Aeff, float* __restrict__ constv)
{
  const int g = blockIdx.x;                 // 0..383
  const int dir = (g >= 192) ? 1 : 0;
  const int grow = dir ? g - 192 : g;
  const float* Wih = dir ? Wih_b : Wih_f;
  const float* bih = dir ? bih_b : bih_f;

  __shared__ float wrow[64*129];
  __shared__ float arow[256];
  const int tid = threadIdx.x;              // 64 threads = 1 wave

  const float4* W4 = (const float4*)(Wih + (size_t)grow*8192);
  for (int i4 = tid; i4 < 2048; i4 += 64) {
    float4 v = W4[i4];
    int base = i4*4, row = base>>7, col = base&127;
    float* dst = &wrow[row*129+col];
    dst[0]=v.x; dst[1]=v.y; dst[2]=v.z; dst[3]=v.w;
  }
  __syncthreads();

  const int n = tid;
  float a0=0.f,a1=0.f,a2=0.f,a3=0.f,cp=0.f;
  for (int c=0;c<64;c++) {
    float w1 = wrow[n*129 + c];
    a0 = fmaf(w1, Wcheb[c],     a0);
    a1 = fmaf(w1, Wcheb[64+c],  a1);
    a2 = fmaf(w1, Wcheb[128+c], a2);
    cp = fmaf(w1, bcheb[c],     cp);
    float w2 = wrow[n*129 + 64 + c];
    a3 = fmaf(w2, Wgcn[c], a3);
    cp = fmaf(w2, bgcn[c], cp);
  }
  arow[n*4+0]=a0; arow[n*4+1]=a1; arow[n*4+2]=a2; arow[n*4+3]=a3;
  for (int off=32; off; off>>=1) cp += __shfl_down(cp, off, 64);
  if (tid==0) constv[g] = cp + bih[grow];
  __syncthreads();

  const int m = tid;
  float ae = arow[m*4+0];
  for (int nn2=0; nn2<64; nn2++) {
    ae = fmaf(arow[nn2*4+1], Lg [nn2*64+m], ae);
    ae = fmaf(arow[nn2*4+2], L2g[nn2*64+m], ae);
    ae = fmaf(arow[nn2*4+3], Gm [nn2*64+m], ae);
  }
  Aeff[g*64+m] = ae;
}

// ---------------------------------------------------------------------------
// K4: xp[12800][384] = X[12800][64] @ Aeff[384][64]^T + constv, with the
// x transpose fused into staging (k3 eliminated).
// ---------------------------------------------------------------------------
__global__ __launch_bounds__(256) void k4_gemm(
    const float* __restrict__ x, const float* __restrict__ Aeff,
    const float* __restrict__ constv, float* __restrict__ xp)
{
  const int m0 = blockIdx.x*64, g0 = blockIdx.y*64;
  __shared__ float sX[64*68];   // [k][m-row], stride 68
  __shared__ float sA[64*68];   // [k][g-row]
  const int tid = threadIdx.x;

  // ---- stage X tile with fused transpose ----
  {
    const int row = tid & 63;            // lane = row (t-direction)
    const int kq  = tid >> 6;            // 0..3
    const int m = m0 + row;
    const int b = m / 200;
    const int t = m - b*200;
    const float* xb = x + (size_t)b*64*200 + t;
    #pragma unroll
    for (int kk=0; kk<16; ++kk) {
      int k = kq*16 + kk;
      sX[k*68 + row] = xb[(size_t)k*200];
    }
  }
  // ---- stage Aeff tile (float4 loads) ----
  {
    const float4* A4 = (const float4*)Aeff;
    #pragma unroll
    for (int i=0;i<4;i++) {
      int f = tid + i*256;
      int r2 = f >> 4, kq2 = f & 15;
      float4 w = A4[(g0+r2)*16 + kq2];
      sA[(kq2*4+0)*68 + r2] = w.x;
      sA[(kq2*4+1)*68 + r2] = w.y;
      sA[(kq2*4+2)*68 + r2] = w.z;
      sA[(kq2*4+3)*68 + r2] = w.w;
    }
  }
  __syncthreads();

  const int tm = tid & 15, tn = tid >> 4;
  float acc[4][4] = {};
  #pragma unroll 8
  for (int k=0;k<64;k++) {
    float4 a  = *(const float4*)&sX[k*68 + tm*4];
    float4 bb = *(const float4*)&sA[k*68 + tn*4];
    float av[4]={a.x,a.y,a.z,a.w}, bv[4]={bb.x,bb.y,bb.z,bb.w};
    #pragma unroll
    for (int i=0;i<4;i++)
      #pragma unroll
      for (int j=0;j<4;j++)
        acc[i][j] = fmaf(av[i], bv[j], acc[i][j]);
  }

  float cv[4];
  #pragma unroll
  for (int j=0;j<4;j++) cv[j] = constv[g0 + tn*4 + j];
  #pragma unroll
  for (int i=0;i<4;i++) {
    int mrow = m0 + tm*4 + i;
    #pragma unroll
    for (int j=0;j<4;j++)
      xp[mrow*384 + g0 + tn*4 + j] = acc[i][j] + cv[j];
  }
}

// ---------------------------------------------------------------------------
// K5: biGRU recurrence — R11-EXACT revert (best measured: 83us, VGPR=132).
// Single wave per (b,dir); lane g owns hidden unit g. h broadcast via LDS
// (ds_write_b16 + 8x broadcast ds_read_b128, upfront). Weights resident as
// fp16 pairs (96 regs); waves_per_eu(1,1) is the ONLY config the allocator
// keeps them resident for (R13/R14/R15 all remat'd and lost >=2x).
// ---------------------------------------------------------------------------
__global__ __launch_bounds__(64)
__attribute__((amdgpu_waves_per_eu(1, 1)))
void k5_gru(
    const float* __restrict__ xp,
    const float* __restrict__ Whh_f, const float* __restrict__ bhh_f,
    const float* __restrict__ Whh_b, const float* __restrict__ bhh_b,
    float* __restrict__ gru_out)
{
  const int bd = blockIdx.x;
  const int b = bd >> 1, dir = bd & 1;
  const int g = threadIdx.x & 63;
  const float* Whh = dir ? Whh_b : Whh_f;
  const float* bhh = dir ? bhh_b : bhh_f;

  // resident fp16-packed weight rows (3 gate rows for this lane's unit)
  h2v wr[32], wz[32], wn[32];
  #pragma unroll
  for (int i=0;i<32;i++){
    float2 a = ((const float2*)(Whh + (size_t)g*64))[i];
    float2 bq= ((const float2*)(Whh + (size_t)(64+g)*64))[i];
    float2 c = ((const float2*)(Whh + (size_t)(128+g)*64))[i];
    wr[i] = h2v{(_Float16)a.x, (_Float16)a.y};
    wz[i] = h2v{(_Float16)bq.x,(_Float16)bq.y};
    wn[i] = h2v{(_Float16)c.x, (_Float16)c.y};
  }
  const float br_ = bhh[g], bz_ = bhh[64+g], bn_ = bhh[128+g];

  __shared__ __align__(16) _Float16 hsh[64];   // packed fp16 h vector (128 B)
  hsh[g] = (_Float16)0.f;                      // initial h = 0

  const int t0 = dir ? (Tt-1) : 0;
  const int tstep = dir ? -1 : 1;
  const float* xb = xp + (size_t)(b*Tt)*384 + dir*192 + g;
  float* gout = gru_out + (size_t)(b*Tt)*128 + dir*64 + g;

  float h = 0.f;
  float xrA = xb[(size_t)t0*384], xzA = xb[(size_t)t0*384+64], xnA = xb[(size_t)t0*384+128];
  const int t1 = t0 + tstep;
  float xrB = xb[(size_t)t1*384], xzB = xb[(size_t)t1*384+64], xnB = xb[(size_t)t1*384+128];

  int t = t0;
  auto STEP = [&](float& xr, float& xz, float& xn){
    // broadcast-read the full packed h vector: 8x ds_read_b128, conflict-free
    h2v hv[32];
    {
      const uint4* hp4 = (const uint4*)hsh;
      #pragma unroll
      for (int q=0;q<8;q++){
        union { uint4 v; h2v p[4]; } uu;
        uu.v = hp4[q];
        hv[q*4+0]=uu.p[0]; hv[q*4+1]=uu.p[1]; hv[q*4+2]=uu.p[2]; hv[q*4+3]=uu.p[3];
      }
    }

    const float cxr = xr, cxz = xz, cxn = xn;
    const int tpre = t + 2*tstep;
    if ((unsigned)tpre < (unsigned)Tt) {   // depth-2 prefetch, reload after use
      xr = xb[(size_t)tpre*384];
      xz = xb[(size_t)tpre*384+64];
      xn = xb[(size_t)tpre*384+128];
    }

    float ar0=0.f,ar1=0.f,az0=0.f,az1=0.f,an0=0.f,an1=0.f;
    #pragma unroll
    for (int i=0;i<32;i+=2){
      ar0 = DOT2(wr[i],  hv[i],  ar0);  az0 = DOT2(wz[i],  hv[i],  az0);  an0 = DOT2(wn[i],  hv[i],  an0);
      ar1 = DOT2(wr[i+1],hv[i+1],ar1);  az1 = DOT2(wz[i+1],hv[i+1],az1);  an1 = DOT2(wn[i+1],hv[i+1],an1);
    }

    float r   = sigm(cxr + (ar0+ar1) + br_);
    float z   = sigm(cxz + (az0+az1) + bz_);
    float nn2 = tanh_fast(cxn + r*((an0+an1) + bn_));
    float hnew = (1.f - z)*nn2 + z*h;
    h = hnew;
    hsh[g] = (_Float16)hnew;               // ds_write_b16 for next step
    gout[(size_t)t*128] = hnew;
    t += tstep;
  };

  for (int sp=0; sp<Tt; sp+=2) { STEP(xrA,xzA,xnA); STEP(xrB,xzB,xnB); }
}

// ---------------------------------------------------------------------------
// K6: attention pooling + classifier. One block per batch item; 4 waves.
// Barrier-lean: wave-level shfl_xor reductions (6 barriers total vs ~26),
// ctx loop split across two t-halves (halves the serial chain).
// ---------------------------------------------------------------------------
__global__ __launch_bounds__(256) void k6_attn(
    const float* __restrict__ gru_out,
    const float* __restrict__ attn_W, const float* __restrict__ attn_b,
    const float* __restrict__ clf_W,  const float* __restrict__ clf_b,
    float* __restrict__ out)
{
  const int b = blockIdx.x, tid = threadIdx.x;
  const int wv = tid >> 6, ln = tid & 63;
  __shared__ float aW[128], cW[128];
  __shared__ float s_s[Tt];
  __shared__ float wred[4];
  __shared__ float part[2][128];
  if (tid < 128) { aW[tid]=attn_W[tid]; cW[tid]=clf_W[tid]; }
  __syncthreads();

  float sc = -1e30f;
  if (tid < Tt) {
    const float* row = gru_out + (size_t)(b*Tt + tid)*128;
    float acc = 0.f;
    for (int j=0;j<128;j++) acc = fmaf(row[j], aW[j], acc);
    sc = tanhf(acc + attn_b[0]);
    s_s[tid] = sc;
  }
  // block max via wave shuffle + 4-entry LDS combine
  float m = sc;
  #pragma unroll
  for (int off=32; off; off>>=1) m = fmaxf(m, __shfl_xor(m, off, 64));
  if (ln==0) wred[wv] = m;
  __syncthreads();
  const float mx = fmaxf(fmaxf(wred[0],wred[1]), fmaxf(wred[2],wred[3]));

  float e = 0.f;
  if (tid < Tt) { e = __expf(sc - mx); s_s[tid] = e; }
  float s = e;
  #pragma unroll
  for (int off=32; off; off>>=1) s += __shfl_xor(s, off, 64);
  __syncthreads();                       // mx reads + s_s writes done
  if (ln==0) wred[wv] = s;
  __syncthreads();
  const float total = wred[0]+wred[1]+wred[2]+wred[3];

  // ctx: j = tid&127, t-half = tid>>7 (100 iters each)
  const int j = tid & 127, half = tid >> 7;
  float c = 0.f;
  const float* gb = gru_out + (size_t)(b*Tt)*128 + j;
  for (int t = half*100; t < half*100 + 100; ++t)
    c = fmaf(s_s[t], gb[(size_t)t*128], c);
  part[half][j] = c;
  __syncthreads();

  float p = 0.f;
  if (tid < 128) p = ((part[0][j] + part[1][j]) / total) * cW[j];
  #pragma unroll
  for (int off=32; off; off>>=1) p += __shfl_xor(p, off, 64);
  __syncthreads();                       // total/part reads done
  if (ln==0) wred[wv] = p;               // waves 2,3 contribute 0
  __syncthreads();
  if (tid==0) out[b] = sigm(wred[0] + wred[1] + clf_b[0]);
}

// ---------------------------------------------------------------------------
extern "C" void kernel_launch(void* const* d_in, const int* in_sizes, int n_in,
                              void* d_out, int out_size, void* d_ws, size_t ws_size,
                              hipStream_t stream)
{
  const float* x      = (const float*)d_in[0];
  const int*   sp_ei  = (const int*)  d_in[1];
  const float* sp_ew  = (const float*)d_in[2];
  const int*   fn_ei  = (const int*)  d_in[3];
  const float* fn_ew  = (const float*)d_in[4];
  const float* Wcheb  = (const float*)d_in[5];
  const float* bcheb  = (const float*)d_in[6];
  const float* Wgcn   = (const float*)d_in[7];
  const float* bgcn   = (const float*)d_in[8];
  const float* Wih_f  = (const float*)d_in[9];
  const float* Whh_f  = (const float*)d_in[10];
  const float* bih_f  = (const float*)d_in[11];
  const float* bhh_f  = (const float*)d_in[12];
  const float* Wih_b  = (const float*)d_in[13];
  const float* Whh_b  = (const float*)d_in[14];
  const float* bih_b  = (const float*)d_in[15];
  const float* bhh_b  = (const float*)d_in[16];
  const float* attn_W = (const float*)d_in[17];
  const float* attn_b = (const float*)d_in[18];
  const float* clf_W  = (const float*)d_in[19];
  const float* clf_b  = (const float*)d_in[20];
  float* out = (float*)d_out;

  float* ws     = (float*)d_ws;
  float* Lg     = ws;                    // 4096
  float* L2g    = Lg   + 4096;           // 4096
  float* Gm     = L2g  + 4096;           // 4096
  float* Aeff   = Gm   + 4096;           // 384*64 = 24576
  float* constv = Aeff + 24576;          // 384 (+pad to 512)
  float* xp     = constv + 512;          // 12800*384 = 4915200
  float* gro    = xp   + 4915200;        // 12800*128 = 1638400

  hipLaunchKernelGGL(k1_graphs,    dim3(1),      dim3(1024), 0, stream,
                     sp_ei, sp_ew, fn_ei, fn_ew, Lg, L2g, Gm);
  hipLaunchKernelGGL(k2_aeff,      dim3(384),    dim3(64),   0, stream,
                     Wih_f, bih_f, Wih_b, bih_b, Wcheb, bcheb, Wgcn, bgcn,
                     Lg, L2g, Gm, Aeff, constv);
  hipLaunchKernelGGL(k4_gemm,      dim3(200, 6), dim3(256),  0, stream,
                     x, Aeff, constv, xp);
  hipLaunchKernelGGL(k5_gru,       dim3(128),    dim3(64),   0, stream,
                     xp, Whh_f, bhh_f, Whh_b, bhh_b, gro);
  hipLaunchKernelGGL(k6_attn,      dim3(64),     dim3(256),  0, stream,
                     gro, attn_W, attn_b, clf_W, clf_b, out);
}